// Round 1
// baseline (98.242 us; speedup 1.0000x reference)
//
#include <hip/hip_runtime.h>

// VQVAE quantization: z [8,4,64,64] f32, codebook [8192,4] f32
// out[0..131072) = z_q in [B,C,H,W]; out[131072] = 1.25 * mean((z_q - z)^2)

#define N_PTS  32768          // B*H*W
#define K_CODES 8192
#define HW     4096           // H*W
#define CHW    16384          // C*H*W
#define K_CHUNKS 8
#define K_PER  (K_CODES / K_CHUNKS)

__global__ __launch_bounds__(256) void vq_init(unsigned long long* keys,
                                               float* norms, float* acc,
                                               const float* __restrict__ cb) {
    int i = blockIdx.x * 256 + threadIdx.x;
    if (i < N_PTS) keys[i] = 0xFFFFFFFFFFFFFFFFULL;
    if (i < K_CODES) {
        float4 e = reinterpret_cast<const float4*>(cb)[i];
        norms[i] = e.x * e.x + e.y * e.y + e.z * e.z + e.w * e.w;
    }
    if (i == 0) *acc = 0.0f;
}

__global__ __launch_bounds__(256) void vq_argmin(const float* __restrict__ z,
                                                 const float* __restrict__ cb,
                                                 const float* __restrict__ norms,
                                                 unsigned long long* keys) {
    int n = blockIdx.x * 256 + threadIdx.x;     // point id
    int b = n >> 12;                            // n / 4096
    int hw = n & 4095;
    const float* zp = z + b * CHW + hw;
    float z0 = zp[0];
    float z1 = zp[HW];
    float z2 = zp[2 * HW];
    float z3 = zp[3 * HW];

    const float4* cb4 = reinterpret_cast<const float4*>(cb);
    int k0 = blockIdx.y * K_PER;                // uniform per block -> s_load path
    float best = 3.4e38f;
    int bestk = 0;
#pragma unroll 8
    for (int k = k0; k < k0 + K_PER; ++k) {
        float4 e = cb4[k];                      // wave-uniform -> scalar load
        float dot = z0 * e.x + z1 * e.y + z2 * e.z + z3 * e.w;
        float score = __builtin_fmaf(-2.0f, dot, norms[k]);
        if (score < best) { best = score; bestk = k; }   // strict < keeps smallest k
    }

    // ordered-float encoding: unsigned compare order == float compare order
    unsigned u = __float_as_uint(best);
    u = (u & 0x80000000u) ? ~u : (u | 0x80000000u);
    unsigned long long key = ((unsigned long long)u << 32) | (unsigned)bestk;
    atomicMin(keys + n, key);                   // min score, tie -> min k
}

__global__ __launch_bounds__(256) void vq_gather(const float* __restrict__ z,
                                                 const float* __restrict__ cb,
                                                 const unsigned long long* __restrict__ keys,
                                                 float* __restrict__ out,
                                                 float* acc) {
    int n = blockIdx.x * 256 + threadIdx.x;
    int b = n >> 12;
    int hw = n & 4095;
    int k = (int)(keys[n] & 0xFFFFFFFFu);
    float4 e = reinterpret_cast<const float4*>(cb)[k];

    const float* zp = z + b * CHW + hw;
    float* op = out + b * CHW + hw;
    float d0 = e.x - zp[0];
    float d1 = e.y - zp[HW];
    float d2 = e.z - zp[2 * HW];
    float d3 = e.w - zp[3 * HW];
    op[0]      = e.x;
    op[HW]     = e.y;
    op[2 * HW] = e.z;
    op[3 * HW] = e.w;

    float s = d0 * d0 + d1 * d1 + d2 * d2 + d3 * d3;
#pragma unroll
    for (int off = 32; off > 0; off >>= 1)
        s += __shfl_down(s, off, 64);
    if ((threadIdx.x & 63) == 0) atomicAdd(acc, s);
}

__global__ void vq_finalize(const float* acc, float* out) {
    if (threadIdx.x == 0 && blockIdx.x == 0)
        out[N_PTS * 4] = 1.25f * (*acc) / (float)(N_PTS * 4);
}

extern "C" void kernel_launch(void* const* d_in, const int* in_sizes, int n_in,
                              void* d_out, int out_size, void* d_ws, size_t ws_size,
                              hipStream_t stream) {
    const float* z  = (const float*)d_in[0];
    const float* cb = (const float*)d_in[1];
    float* out = (float*)d_out;

    unsigned long long* keys = (unsigned long long*)d_ws;                    // 256 KB
    float* norms = (float*)((char*)d_ws + N_PTS * 8);                       // 32 KB
    float* acc   = (float*)((char*)d_ws + N_PTS * 8 + K_CODES * 4);         // 4 B

    vq_init<<<N_PTS / 256, 256, 0, stream>>>(keys, norms, acc, cb);

    dim3 grid(N_PTS / 256, K_CHUNKS);
    vq_argmin<<<grid, 256, 0, stream>>>(z, cb, norms, keys);

    vq_gather<<<N_PTS / 256, 256, 0, stream>>>(z, cb, keys, out, acc);

    vq_finalize<<<1, 64, 0, stream>>>(acc, out);
}

// Round 2
// 58.480 us; speedup vs baseline: 1.6799x; 1.6799x over previous
//
#include <hip/hip_runtime.h>

// VQVAE quantization: z [8,4,64,64] f32, codebook [8192,4] f32
// out[0..131072) = z_q in [B,C,H,W]; out[131072] = 1.25 * mean((z_q - z)^2)
//
// argmin_k ||e_k||^2 - 2 z.e_k  ==  argmax_k t_k,  t_k = 0.5 + 64*(z.e_k - ||e_k||^2/2)
// t_k in (0.36, 0.64) > 0 always, so as_uint(t) is order-preserving; cross-chunk
// combine via atomicMin on (~as_uint(t) << 32 | k)  -> max t, tie -> min k.

#define N_PTS   32768          // B*H*W
#define K_CODES 8192
#define HW      4096           // H*W
#define CHW     16384          // C*H*W
#define K_CHUNKS 32
#define K_PER   (K_CODES / K_CHUNKS)   // 256
#define P       4                       // points per thread
#define PTS_PER_BLOCK (256 * P)         // 1024
#define PT_BLOCKS (N_PTS / PTS_PER_BLOCK) // 32

__global__ __launch_bounds__(256) void vq_init(unsigned long long* keys, float* acc) {
    int i = blockIdx.x * 256 + threadIdx.x;
    keys[i] = 0xFFFFFFFFFFFFFFFFULL;
    if (i == 0) *acc = 0.0f;
}

__global__ __launch_bounds__(256) void vq_argmin(const float* __restrict__ z,
                                                 const float* __restrict__ cb,
                                                 unsigned long long* __restrict__ keys) {
    __shared__ float4 se[K_PER];
    __shared__ float  sc[K_PER];
    const int t = threadIdx.x;
    const int k0 = blockIdx.y * K_PER;

    // stage this block's codebook chunk into LDS (coalesced float4 loads)
    {
        float4 e = reinterpret_cast<const float4*>(cb)[k0 + t];
        sc[t] = 0.5f - 32.0f * (e.x * e.x + e.y * e.y + e.z * e.z + e.w * e.w);
        se[t] = e;
    }
    __syncthreads();

    // load P points, pre-scaled by 64 (folds the x64 into the dot product)
    const int nbase = blockIdx.x * PTS_PER_BLOCK + t;
    float zx[P], zy[P], zz[P], zw[P];
#pragma unroll
    for (int p = 0; p < P; ++p) {
        int n = nbase + p * 256;
        int b = n >> 12;                // n / 4096
        int hw = n & 4095;
        const float* zp = z + b * CHW + hw;
        zx[p] = 64.0f * zp[0];
        zy[p] = 64.0f * zp[HW];
        zz[p] = 64.0f * zp[2 * HW];
        zw[p] = 64.0f * zp[3 * HW];
    }

    float best[P];
    int   bestk[P];
#pragma unroll
    for (int p = 0; p < P; ++p) { best[p] = 0.0f; bestk[p] = 0; }

#pragma unroll 4
    for (int k = 0; k < K_PER; ++k) {
        float4 e = se[k];               // uniform addr -> broadcast, no conflicts
        float  c = sc[k];
#pragma unroll
        for (int p = 0; p < P; ++p) {
            float tt = __builtin_fmaf(zx[p], e.x, c);
            tt = __builtin_fmaf(zy[p], e.y, tt);
            tt = __builtin_fmaf(zz[p], e.z, tt);
            tt = __builtin_fmaf(zw[p], e.w, tt);
            if (tt > best[p]) { best[p] = tt; bestk[p] = k; }  // strict > keeps min k
        }
    }

#pragma unroll
    for (int p = 0; p < P; ++p) {
        unsigned u = ~__float_as_uint(best[p]);   // t>0 -> as_uint monotone; ~ flips to min
        unsigned long long key =
            ((unsigned long long)u << 32) | (unsigned)(k0 + bestk[p]);
        atomicMin(keys + nbase + p * 256, key);
    }
}

__global__ __launch_bounds__(256) void vq_gather(const float* __restrict__ z,
                                                 const float* __restrict__ cb,
                                                 const unsigned long long* __restrict__ keys,
                                                 float* __restrict__ out,
                                                 float* acc) {
    int n = blockIdx.x * 256 + threadIdx.x;
    int b = n >> 12;
    int hw = n & 4095;
    int k = (int)(keys[n] & 0xFFFFFFFFu);
    float4 e = reinterpret_cast<const float4*>(cb)[k];

    const float* zp = z + b * CHW + hw;
    float* op = out + b * CHW + hw;
    float d0 = e.x - zp[0];
    float d1 = e.y - zp[HW];
    float d2 = e.z - zp[2 * HW];
    float d3 = e.w - zp[3 * HW];
    op[0]      = e.x;
    op[HW]     = e.y;
    op[2 * HW] = e.z;
    op[3 * HW] = e.w;

    float s = d0 * d0 + d1 * d1 + d2 * d2 + d3 * d3;
#pragma unroll
    for (int off = 32; off > 0; off >>= 1)
        s += __shfl_down(s, off, 64);
    if ((threadIdx.x & 63) == 0) atomicAdd(acc, s);
}

__global__ void vq_finalize(const float* acc, float* out) {
    if (threadIdx.x == 0 && blockIdx.x == 0)
        out[N_PTS * 4] = 1.25f * (*acc) / (float)(N_PTS * 4);
}

extern "C" void kernel_launch(void* const* d_in, const int* in_sizes, int n_in,
                              void* d_out, int out_size, void* d_ws, size_t ws_size,
                              hipStream_t stream) {
    const float* z  = (const float*)d_in[0];
    const float* cb = (const float*)d_in[1];
    float* out = (float*)d_out;

    unsigned long long* keys = (unsigned long long*)d_ws;            // 256 KB
    float* acc = (float*)((char*)d_ws + N_PTS * 8);                  // 4 B

    vq_init<<<N_PTS / 256, 256, 0, stream>>>(keys, acc);

    dim3 grid(PT_BLOCKS, K_CHUNKS);
    vq_argmin<<<grid, 256, 0, stream>>>(z, cb, keys);

    vq_gather<<<N_PTS / 256, 256, 0, stream>>>(z, cb, keys, out, acc);

    vq_finalize<<<1, 64, 0, stream>>>(acc, out);
}